// Round 1
// baseline (490.565 us; speedup 1.0000x reference)
//
#include <hip/hip_runtime.h>

#define D_DIM 764
#define DP    768
#define BM    128
#define BN    128
#define BK    32

typedef __attribute__((ext_vector_type(8))) short bf16x8;
typedef __attribute__((ext_vector_type(4))) float f32x4;

typedef __attribute__((address_space(3))) char lds_char;
typedef __attribute__((address_space(1))) const char g_char;

__device__ inline unsigned short f2bf(float f) {
    union { float f; unsigned u; } v; v.f = f;
    unsigned r = v.u + 0x7FFFu + ((v.u >> 16) & 1u);  // RNE
    return (unsigned short)(r >> 16);
}

// Mask (k < n), cast to bf16, pad to DP x DP. Layout: Wb[n][k] (BT form, K-contiguous).
__global__ void prep_w(const float* __restrict__ W, unsigned short* __restrict__ Wb) {
    int idx = blockIdx.x * blockDim.x + threadIdx.x;   // 0 .. DP*DP-1
    int n = idx / DP, k = idx - n * DP;
    float v = 0.0f;
    if (n < D_DIM && k < n) v = W[n * D_DIM + k];
    Wb[idx] = f2bf(v);
}

__global__ __launch_bounds__(256, 2) void fvsbn_gemm(
    const float* __restrict__ X,          // [65536, 764] fp32
    const unsigned short* __restrict__ Wb,// [768, 768] bf16 masked (BT layout)
    const float* __restrict__ bias,       // [764] fp32
    float* __restrict__ out)              // [65536, 764] fp32
{
    __shared__ __align__(16) unsigned short As[BM * BK]; // [row][k] 8 KB
    __shared__ __align__(16) unsigned short Bs[BN * BK]; // [n][k]   8 KB

    const int tid  = threadIdx.x;
    const int lane = tid & 63;
    const int wid  = tid >> 6;        // 0..3
    const int wm   = wid & 1;         // wave row (2x2 wave grid)
    const int wn   = wid >> 1;        // wave col
    const int quad = lane >> 4;
    const int l16  = lane & 15;

    const int bid = blockIdx.x;       // 0 .. 512*6-1, n-tile fastest for x reuse
    const int nt  = bid % 6;
    const int mt  = bid / 6;
    const int m0  = mt * BM;
    const int n0  = nt * BN;

    // Triangular skip: cols [n0, n0+127] only use k <= n0+126 (plus zero-pad).
    const int num_k = (n0 + BN) / BK;  // 4,8,12,16,20,24

    f32x4 acc[4][4];
#pragma unroll
    for (int i = 0; i < 4; ++i)
#pragma unroll
        for (int j = 0; j < 4; ++j) acc[i][j] = (f32x4){0.f, 0.f, 0.f, 0.f};

    for (int kk = 0; kk < num_k; ++kk) {
        const int k0 = kk * BK;

        // ---- stage B (bf16, pre-masked) via async global->LDS, 16B chunks ----
#pragma unroll
        for (int j = 0; j < 2; ++j) {
            const int cbase = (wid * 2 + j) * 64;      // wave-uniform chunk base
            const int c     = cbase + lane;            // 0..511
            const int row   = c >> 2;                  // 0..127
            const int cw    = c & 3;                   // 16B chunk within row
            const unsigned short* gp = Wb + (size_t)(n0 + row) * DP + k0 + cw * 8;
            __builtin_amdgcn_global_load_lds((g_char*)gp,
                                             (lds_char*)((char*)Bs + cbase * 16),
                                             16, 0, 0);
        }

        // ---- stage A: fp32 global -> bf16 LDS (4 float4 per thread) ----
#pragma unroll
        for (int i = 0; i < 4; ++i) {
            const int s   = tid + i * 256;             // 0..1023
            const int row = s >> 3;                    // 0..127
            const int f4  = s & 7;
            const int k   = k0 + f4 * 4;
            ushort4 pk;
            if (k < D_DIM) {
                float4 xv = *(const float4*)(X + (size_t)(m0 + row) * D_DIM + k);
                pk.x = f2bf(xv.x); pk.y = f2bf(xv.y);
                pk.z = f2bf(xv.z); pk.w = f2bf(xv.w);
            } else {
                pk.x = 0; pk.y = 0; pk.z = 0; pk.w = 0;
            }
            *(ushort4*)&As[row * BK + f4 * 4] = pk;
        }

        __syncthreads();  // drains vmcnt (global_load_lds) + lgkmcnt (ds_write)

        // ---- K-step: 8 ds_read_b128 + 16 MFMA per wave ----
        bf16x8 af[4], bf[4];
#pragma unroll
        for (int mi = 0; mi < 4; ++mi)
            af[mi] = *(const bf16x8*)&As[(wm * 64 + mi * 16 + l16) * BK + quad * 8];
#pragma unroll
        for (int ni = 0; ni < 4; ++ni)
            bf[ni] = *(const bf16x8*)&Bs[(wn * 64 + ni * 16 + l16) * BK + quad * 8];

#pragma unroll
        for (int mi = 0; mi < 4; ++mi)
#pragma unroll
            for (int ni = 0; ni < 4; ++ni)
                acc[mi][ni] = __builtin_amdgcn_mfma_f32_16x16x32_bf16(
                    af[mi], bf[ni], acc[mi][ni], 0, 0, 0);

        __syncthreads();  // before next iteration overwrites tiles
    }

    // ---- epilogue: + bias, store fp32 (col bound-checked vs 764) ----
#pragma unroll
    for (int ni = 0; ni < 4; ++ni) {
        const int col = n0 + wn * 64 + ni * 16 + l16;
        if (col < D_DIM) {
            const float bv = bias[col];
#pragma unroll
            for (int mi = 0; mi < 4; ++mi) {
                const int row = m0 + wm * 64 + mi * 16 + quad * 4;
#pragma unroll
                for (int r = 0; r < 4; ++r)
                    out[(size_t)(row + r) * D_DIM + col] = acc[mi][ni][r] + bv;
            }
        }
    }
}

extern "C" void kernel_launch(void* const* d_in, const int* in_sizes, int n_in,
                              void* d_out, int out_size, void* d_ws, size_t ws_size,
                              hipStream_t stream) {
    const float* X    = (const float*)d_in[0];
    const float* W    = (const float*)d_in[1];
    const float* bias = (const float*)d_in[2];
    float* out        = (float*)d_out;
    unsigned short* Wb = (unsigned short*)d_ws;  // DP*DP bf16 = 1.18 MB

    prep_w<<<(DP * DP) / 256, 256, 0, stream>>>(W, Wb);
    fvsbn_gemm<<<(65536 / BM) * (DP / BN), 256, 0, stream>>>(X, Wb, bias, out);
}

// Round 2
// 466.182 us; speedup vs baseline: 1.0523x; 1.0523x over previous
//
#include <hip/hip_runtime.h>

#define D_DIM 764
#define DP    768
#define BM    128
#define BN    128
#define BK    64

typedef __attribute__((ext_vector_type(8))) short bf16x8;
typedef __attribute__((ext_vector_type(8))) unsigned short u16x8;
typedef __attribute__((ext_vector_type(4))) float f32x4;

typedef __attribute__((address_space(3))) char lds_char;
typedef __attribute__((address_space(1))) const char g_char;

__device__ inline unsigned short f2bf(float f) {
    union { float f; unsigned u; } v; v.f = f;
    unsigned r = v.u + 0x7FFFu + ((v.u >> 16) & 1u);  // RNE
    return (unsigned short)(r >> 16);
}

// Mask (k < n), cast to bf16, pad to DP x DP. Layout: Wb[n][k] (BT form, K-contiguous).
__global__ void prep_w(const float* __restrict__ W, unsigned short* __restrict__ Wb) {
    int idx = blockIdx.x * blockDim.x + threadIdx.x;   // 0 .. DP*DP-1
    int n = idx / DP, k = idx - n * DP;
    float v = 0.0f;
    if (n < D_DIM && k < n) v = W[n * D_DIM + k];
    Wb[idx] = f2bf(v);
}

// 128x128 tile, BK=64, 4 waves (2x2), 16x16x32 bf16 MFMA.
// LDS layout: row r of a tile = 8 chunks of 16B; chunk position c holds
// global chunk (c ^ (r&7))  -> bank-balanced ds_read_b128 + valid
// global_load_lds (uniform base + lane*16).
__global__ __launch_bounds__(256, 4) void fvsbn_gemm(
    const float* __restrict__ X,          // [65536, 764] fp32
    const unsigned short* __restrict__ Wb,// [768, 768] bf16 masked (BT layout)
    const float* __restrict__ bias,       // [764] fp32
    float* __restrict__ out)              // [65536, 764] fp32
{
    __shared__ __align__(16) unsigned short As[BM * BK]; // 16 KB
    __shared__ __align__(16) unsigned short Bs[BN * BK]; // 16 KB

    const int tid  = threadIdx.x;
    const int lane = tid & 63;
    const int wid  = tid >> 6;        // 0..3
    const int wm   = wid & 1;
    const int wn   = wid >> 1;
    const int quad = lane >> 4;
    const int l16  = lane & 15;

    // XCD-aware swizzle: 512 m-tiles x 6 n-tiles. Blocks dispatched round-robin
    // over 8 XCDs; give each XCD contiguous m-tiles with nt fastest so the 6
    // n-tile blocks sharing an m-tile's x rows are adjacent on ONE XCD's L2.
    const int bid = blockIdx.x;       // 0..3071
    const int xcd = bid & 7;
    const int j   = bid >> 3;         // 0..383
    const int nt  = j % 6;
    const int jm  = j / 6;            // 0..63
    const int mt  = jm * 8 + xcd;     // 0..511
    const int m0  = mt * BM;
    const int n0  = nt * BN;

    // Triangular skip: cols [n0, n0+127] need k <= n0+126.
    const int num_k = (n0 + BN) / BK;  // 2,4,6,8,10,12

    f32x4 acc[4][4];
#pragma unroll
    for (int i = 0; i < 4; ++i)
#pragma unroll
        for (int jj = 0; jj < 4; ++jj) acc[i][jj] = (f32x4){0.f, 0.f, 0.f, 0.f};

    for (int kk = 0; kk < num_k; ++kk) {
        const int k0 = kk * BK;

        // ---- stage B: 128 rows x 128 B = 64 16B-chunks per wave-iter ----
#pragma unroll
        for (int jj = 0; jj < 4; ++jj) {
            const int cbase = (wid * 4 + jj) * 64;       // wave-uniform
            const int c     = cbase + lane;              // 0..1023
            const int r     = c >> 3;
            const int cc    = c & 7;
            const int g     = cc ^ (r & 7);              // swizzled global chunk
            const unsigned short* gp = Wb + (size_t)(n0 + r) * DP + k0 + g * 8;
            __builtin_amdgcn_global_load_lds((g_char*)gp,
                                             (lds_char*)((char*)Bs + cbase * 16),
                                             16, 0, 0);
        }

        // ---- stage A: fp32 -> bf16, 16B (8 elems) per position ----
#pragma unroll
        for (int i = 0; i < 4; ++i) {
            const int p  = tid + i * 256;                // 0..1023
            const int r  = p >> 3;
            const int cc = p & 7;
            const int g  = cc ^ (r & 7);
            const int k  = k0 + g * 8;
            const float* xp = X + (size_t)(m0 + r) * D_DIM + k;
            float4 lo = *(const float4*)xp;              // k <= 760 < 764 always
            float4 hi = (k + 8 <= D_DIM) ? *(const float4*)(xp + 4)
                                         : make_float4(0.f, 0.f, 0.f, 0.f);
            u16x8 pk;
            pk[0] = f2bf(lo.x); pk[1] = f2bf(lo.y); pk[2] = f2bf(lo.z); pk[3] = f2bf(lo.w);
            pk[4] = f2bf(hi.x); pk[5] = f2bf(hi.y); pk[6] = f2bf(hi.z); pk[7] = f2bf(hi.w);
            *(u16x8*)&As[r * BK + cc * 8] = pk;
        }

        __syncthreads();  // drains vmcnt (global_load_lds) + lgkmcnt (ds_write)

        // ---- K-step: 2 sub-steps of (8 ds_read_b128 + 16 MFMA) ----
#pragma unroll
        for (int s = 0; s < 2; ++s) {
            bf16x8 af[4], bfr[4];
#pragma unroll
            for (int mi = 0; mi < 4; ++mi) {
                const int r = wm * 64 + mi * 16 + l16;
                const int g = s * 4 + quad;
                af[mi] = *(const bf16x8*)&As[r * BK + (g ^ (r & 7)) * 8];
            }
#pragma unroll
            for (int ni = 0; ni < 4; ++ni) {
                const int r = wn * 64 + ni * 16 + l16;
                const int g = s * 4 + quad;
                bfr[ni] = *(const bf16x8*)&Bs[r * BK + (g ^ (r & 7)) * 8];
            }
#pragma unroll
            for (int mi = 0; mi < 4; ++mi)
#pragma unroll
                for (int ni = 0; ni < 4; ++ni)
                    acc[mi][ni] = __builtin_amdgcn_mfma_f32_16x16x32_bf16(
                        af[mi], bfr[ni], acc[mi][ni], 0, 0, 0);
        }

        __syncthreads();  // before next iteration overwrites tiles
    }

    // ---- epilogue: + bias, store fp32 (col bound-checked vs 764) ----
#pragma unroll
    for (int ni = 0; ni < 4; ++ni) {
        const int col = n0 + wn * 64 + ni * 16 + l16;
        if (col < D_DIM) {
            const float bv = bias[col];
#pragma unroll
            for (int mi = 0; mi < 4; ++mi) {
                const int row = m0 + wm * 64 + mi * 16 + quad * 4;
#pragma unroll
                for (int r = 0; r < 4; ++r)
                    out[(size_t)(row + r) * D_DIM + col] = acc[mi][ni][r] + bv;
            }
        }
    }
}

extern "C" void kernel_launch(void* const* d_in, const int* in_sizes, int n_in,
                              void* d_out, int out_size, void* d_ws, size_t ws_size,
                              hipStream_t stream) {
    const float* X    = (const float*)d_in[0];
    const float* W    = (const float*)d_in[1];
    const float* bias = (const float*)d_in[2];
    float* out        = (float*)d_out;
    unsigned short* Wb = (unsigned short*)d_ws;  // DP*DP bf16 = 1.18 MB

    prep_w<<<(DP * DP) / 256, 256, 0, stream>>>(W, Wb);
    fvsbn_gemm<<<(65536 / BM) * (DP / BN), 256, 0, stream>>>(X, Wb, bias, out);
}